// Round 5
// baseline (2651.567 us; speedup 1.0000x reference)
//
#include <hip/hip_runtime.h>
#include <hip/hip_bf16.h>

#define T_ 512
#define B_ 64
#define OBS_ 512
#define H_ 1024
#define A_ 18
#define MM_ (T_*B_)   // 32768
#define G4_ (4*H_)    // 4096
#define CH_ 64        // fallback: time steps per chunk
#define NCH_ (T_/CH_) // 8 chunks
#define CM_ (CH_*B_)  // 4096 rows per chunk

typedef unsigned short u16;
typedef unsigned long long u64;
typedef __attribute__((ext_vector_type(8))) short s8v;
typedef __attribute__((ext_vector_type(4))) float f4v;

__device__ __forceinline__ float b2f(u16 u){
    unsigned x = ((unsigned)u) << 16;
    return __builtin_bit_cast(float, x);
}
__device__ __forceinline__ u16 f2b(float f){
    unsigned x = __builtin_bit_cast(unsigned, f);
    return (u16)((x + 0x7fffu + ((x >> 16) & 1u)) >> 16);  // RNE
}

// fast sigmoid/tanh: v_exp + v_rcp (error << bf16 quantum; correct at +-inf)
__device__ __forceinline__ float fsig(float x){
    return __builtin_amdgcn_rcpf(1.f + __expf(-x));
}
__device__ __forceinline__ float ftanh(float x){
    return 1.f - 2.f * __builtin_amdgcn_rcpf(__expf(2.f * x) + 1.f);
}

// async global->LDS, 16B per lane (m97 pattern: wave-uniform LDS base + lane*16)
__device__ __forceinline__ void gl_lds16(const u16* g, u16* l){
    __builtin_amdgcn_global_load_lds(
        (const __attribute__((address_space(1))) unsigned int*)g,
        (__attribute__((address_space(3))) unsigned int*)l, 16, 0, 0);
}

// ---------------- prologue: all casts + bias + zeroing in ONE dispatch ----------------

__global__ void prep_all(const float* __restrict__ Wenc, const float* __restrict__ Wih,
                         const float* __restrict__ Whh, const float* __restrict__ Wdec,
                         const float* __restrict__ bih, const float* __restrict__ bhh,
                         const float* __restrict__ obs,
                         u16* __restrict__ wenc_b, u16* __restrict__ wih_b,
                         u16* __restrict__ whh_b, u16* __restrict__ wdec_b,
                         float* __restrict__ bias2, u16* __restrict__ obs_b,
                         u16* __restrict__ h0buf,
                         float* __restrict__ c_f32, unsigned* __restrict__ flags)
{
    int i = blockIdx.x * blockDim.x + threadIdx.x;
    int stride = gridDim.x * blockDim.x;
    for (int k = i; k < G4_ * H_; k += stride){
        wih_b[k] = f2b(Wih[k]);
        whh_b[k] = f2b(Whh[k]);
    }
    for (int k = i; k < MM_ * OBS_; k += stride) obs_b[k] = f2b(obs[k]);
    for (int k = i; k < H_ * OBS_; k += stride) wenc_b[k] = f2b(Wenc[k]);
    for (int k = i; k < A_ * H_; k += stride) wdec_b[k] = f2b(Wdec[k]);
    for (int k = i; k < G4_; k += stride) bias2[k] = bih[k] + bhh[k];
    unsigned* h0 = (unsigned*)h0buf;
    for (int k = i; k < B_ * H_ / 2; k += stride) h0[k] = 0u;
    for (int k = i; k < B_ * H_; k += stride) c_f32[k] = 0.f;
    for (int k = i; k < 1024; k += stride) flags[k] = 0u;
}

__global__ void copy_hc(const float* __restrict__ h, const float* __restrict__ c,
                        float* __restrict__ out){
    int i = blockIdx.x * blockDim.x + threadIdx.x;  // 65536 threads
    out[(size_t)MM_*A_ + i] = h[i];
    out[(size_t)MM_*A_ + B_*H_ + i] = c[i];
}

// ---------------- bf16 MFMA GEMM (m97 structure): C = act(A @ W^T + bias) --------
// A bf16 [M][K], W bf16 [N][K]. 128x128 tile, BK=64, linear LDS [128][64],
// global_load_lds width-16 staging (4 issues/thread per operand per K-step),
// 2 barriers per K-step. m97-verified layout: LDS dest = linear idx*16B which
// coincides with row-major [row][64] for idx=(row*8+ch).

template<bool RELU>
__global__ __launch_bounds__(256) void gemm_bt(
    const u16* __restrict__ A, const u16* __restrict__ W,
    const float* __restrict__ bias, u16* __restrict__ C,
    int M, int N, int K)
{
    __shared__ __align__(16) u16 As[128 * 64];
    __shared__ __align__(16) u16 Bs[128 * 64];

    const int tid  = threadIdx.x;
    const int lane = tid & 63;
    const int wid  = tid >> 6;
    const int wm   = wid & 1, wn = wid >> 1;
    const int m0   = blockIdx.y * 128, n0 = blockIdx.x * 128;
    const int quad = lane >> 4, l16 = lane & 15;

    f4v acc[4][4];
    #pragma unroll
    for (int i = 0; i < 4; i++)
        #pragma unroll
        for (int j = 0; j < 4; j++) acc[i][j] = (f4v){0.f,0.f,0.f,0.f};

    for (int k0 = 0; k0 < K; k0 += 64){
        __syncthreads();
        #pragma unroll
        for (int ps = 0; ps < 4; ps++){
            int idx = ps * 256 + tid;          // 0..1023
            int row = idx >> 3, ch = idx & 7;  // 16B chunk ch of row
            gl_lds16(A + (size_t)(m0 + row) * K + k0 + ch * 8, &As[idx * 8]);
            gl_lds16(W + (size_t)(n0 + row) * K + k0 + ch * 8, &Bs[idx * 8]);
        }
        asm volatile("s_waitcnt vmcnt(0)" ::: "memory");
        __syncthreads();

        #pragma unroll
        for (int kk = 0; kk < 64; kk += 32){
            s8v af[4], bf[4];
            #pragma unroll
            for (int mt = 0; mt < 4; mt++)
                af[mt] = *(const s8v*)&As[(wm*64 + mt*16 + l16) * 64 + kk + quad*8];
            #pragma unroll
            for (int nt = 0; nt < 4; nt++)
                bf[nt] = *(const s8v*)&Bs[(wn*64 + nt*16 + l16) * 64 + kk + quad*8];
            #pragma unroll
            for (int mt = 0; mt < 4; mt++)
                #pragma unroll
                for (int nt = 0; nt < 4; nt++)
                    acc[mt][nt] = __builtin_amdgcn_mfma_f32_16x16x32_bf16(
                        af[mt], bf[nt], acc[mt][nt], 0, 0, 0);
        }
    }

    #pragma unroll
    for (int mt = 0; mt < 4; mt++){
        #pragma unroll
        for (int nt = 0; nt < 4; nt++){
            #pragma unroll
            for (int r = 0; r < 4; r++){
                int m = m0 + wm*64 + mt*16 + quad*4 + r;
                int n = n0 + wn*64 + nt*16 + l16;
                float v = acc[mt][nt][r] + bias[n];
                if (RELU) v = fmaxf(v, 0.f);
                C[(size_t)m * N + n] = f2b(v);
            }
        }
    }
}

// ---------------- persistent LSTM scan, PER-WAVE flag rendezvous (R4 protocol) ----
// 256 blocks = 4 batch-groups (16 rows) x 64 N-slices (16 units). Generic over
// (t0, nsteps, seed): big path runs ONE dispatch (t0=0, nsteps=512, h_hist =
// h_all[513], seed=null); fallback runs per-chunk (nsteps=64, seed=h_hist for
// next-chunk h[0]). Poll is PIPELINED: two flag samples in flight breaks the
// serial load->check->load RT chain (detection quantization ~RT -> ~RT/2).
// Monotonic flags make any sample order safe.

__global__ __launch_bounds__(256, 1) void lstm_scan(
    const u16* __restrict__ xg,      // [nsteps][64][4096]
    const u16* __restrict__ Whh,     // [4096][1024]
    u16* __restrict__ h_hist,        // [nsteps+1][64][1024]; [0] = incoming h
    float* __restrict__ c_glob,      // [64][1024] fp32
    float* __restrict__ h_f32,       // final-h staging (t == T-1 only)
    const float* __restrict__ mask,  // [nsteps][64]
    unsigned* __restrict__ flags,    // [4][64][4] per-wave monotonic step flags
    int t0, int nsteps, u16* __restrict__ seed)
{
    __shared__ float red[4][4][16][17];  // [wave][gate][batch][unit(+pad)] ~17.4 KB

    const int tid  = threadIdx.x;
    const int lane = tid & 63;
    const int w    = tid >> 6;
    const int quad = lane >> 4, l16 = lane & 15;
    const int bid  = blockIdx.x;
    const int g = bid & 3, s = bid >> 2;
    const int rb0 = g * 16, j0 = s * 16;

    // Whh B-fragments: B[n=lane&15][k=quad*8+j] [m89]
    const int koff = w * 256;
    s8v bf[4][8];
    #pragma unroll
    for (int gate = 0; gate < 4; gate++)
        #pragma unroll
        for (int ks = 0; ks < 8; ks++)
            bf[gate][ks] = *(const s8v*)(
                Whh + (size_t)(gate * H_ + j0 + l16) * H_ + koff + ks * 32 + quad * 8);

    const int cb = tid >> 4, cu = tid & 15;
    const size_t cidx = (size_t)(rb0 + cb) * H_ + j0 + cu;
    float c_reg = c_glob[cidx];

    const size_t hoff = (size_t)(rb0 + l16) * H_ + koff + quad * 8;  // u16 elems

    // producer: flags[g][s][w]; consumer wave w: flags[g][16w + lane>>2][lane&3]
    unsigned* myflag = flags + (g << 8) + (s << 2) + w;
    const unsigned* pollp = flags + (g << 8) + (w << 6) + lane;

    // prefetch xg + mask for st = 0
    const u16* xg0 = xg + (size_t)(rb0 + cb) * G4_ + j0 + cu;
    u16 nxi = xg0[0], nxf = xg0[H_], nxv = xg0[2 * H_], nxo = xg0[3 * H_];
    float nm = mask[rb0 + cb];

    for (int st = 0; st < nsteps; st++){
        const float xi = b2f(nxi), xf = b2f(nxf), xv = b2f(nxv), xo = b2f(nxo);
        const float m = nm;

        // ---- pipelined flag poll: 2 samples in flight
        const unsigned tgt = (unsigned)(t0 + st);
        {
            unsigned f = __hip_atomic_load(pollp, __ATOMIC_RELAXED, __HIP_MEMORY_SCOPE_AGENT);
            int tries = 0;
            for (;;){
                unsigned fn = __hip_atomic_load(pollp, __ATOMIC_RELAXED, __HIP_MEMORY_SCOPE_AGENT);
                if (__all((int)(f >= tgt))) break;   // check older sample; fn in flight
                f = fn;
                if (++tries > (1 << 20)) break;      // backstop: fail visibly, never hang
                if (tries >= 8) __builtin_amdgcn_s_sleep(1);
            }
        }

        // ---- h loads (fresh: first touch after gate) + MFMA
        const u16* hs = h_hist + (size_t)st * B_ * H_ + hoff;
        f4v acc[4];
        #pragma unroll
        for (int gate = 0; gate < 4; gate++) acc[gate] = (f4v){0.f,0.f,0.f,0.f};
        #pragma unroll
        for (int ks = 0; ks < 8; ks++){
            s8v af = *(const s8v*)(hs + ks * 32);
            #pragma unroll
            for (int gate = 0; gate < 4; gate++)
                acc[gate] = __builtin_amdgcn_mfma_f32_16x16x32_bf16(af, bf[gate][ks], acc[gate], 0, 0, 0);
        }
        #pragma unroll
        for (int gate = 0; gate < 4; gate++)
            #pragma unroll
            for (int r = 0; r < 4; r++)
                red[w][gate][quad * 4 + r][l16] = acc[gate][r];
        __syncthreads();  // SYNC1: red[] complete before cell reads

        // ---- cell phase (fast transcendental forms)
        float gi = xi, gf = xf, gg = xv, go = xo;
        #pragma unroll
        for (int ww = 0; ww < 4; ww++){
            gi += red[ww][0][cb][cu];
            gf += red[ww][1][cb][cu];
            gg += red[ww][2][cb][cu];
            go += red[ww][3][cb][cu];
        }

        float is = fsig(gi);
        float fs = fsig(gf);
        float os = fsig(go);
        float gt = ftanh(gg);

        float cn = fs * c_reg + is * gt;
        float hn = os * ftanh(cn);
        hn *= m; cn *= m;
        c_reg = cn;
        if (t0 + st == T_ - 1) h_f32[cidx] = hn;

        // ---- publish h(st+1): packed u32 sc1 store to LLC (this wave: rows 4w..4w+3)
        unsigned hb = (unsigned)f2b(hn);
        unsigned partner = (unsigned)__shfl_xor((int)hb, 1, 64);
        if ((cu & 1) == 0){
            unsigned packed = hb | (partner << 16);
            unsigned* dst = (unsigned*)(h_hist + (size_t)(st + 1) * B_ * H_ + cidx);
            __hip_atomic_store(dst, packed, __ATOMIC_RELAXED, __HIP_MEMORY_SCOPE_AGENT);
            if (seed && st == nsteps - 1){  // seed next chunk's h[0] (fallback only)
                unsigned* dst0 = (unsigned*)(seed + cidx);
                __hip_atomic_store(dst0, packed, __ATOMIC_RELAXED, __HIP_MEMORY_SCOPE_AGENT);
            }
        }
        asm volatile("s_waitcnt vmcnt(0)" ::: "memory");  // this wave's h stores acked

        // ---- release: THIS WAVE's flag (covers exactly this wave's stores)
        if (lane == 0)
            __hip_atomic_store(myflag, (unsigned)(t0 + st + 1),
                               __ATOMIC_RELAXED, __HIP_MEMORY_SCOPE_AGENT);

        // ---- prefetch next step's xg/mask (outside vmcnt window)
        if (st + 1 < nsteps){
            const u16* xgn = xg + (size_t)(st + 1) * B_ * G4_ + (size_t)(rb0 + cb) * G4_ + j0 + cu;
            nxi = xgn[0]; nxf = xgn[H_]; nxv = xgn[2 * H_]; nxo = xgn[3 * H_];
            nm = mask[(size_t)(st + 1) * B_ + rb0 + cb];
        }

        __syncthreads();  // SYNC2 (off publish path): guards red[] reuse
    }

    c_glob[cidx] = c_reg;
}

// ---------------- decode ----------------

__global__ __launch_bounds__(256) void decode_kernel(
    const u16* __restrict__ latent, const u16* __restrict__ Wdec,
    const float* __restrict__ bdec, const float* __restrict__ mask,
    float* __restrict__ values, int rows)
{
    __shared__ __align__(16) u16 wl[A_ * H_];
    const int tid = threadIdx.x;
    for (int i = tid; i < A_ * H_ / 8; i += 256)
        ((uint4*)wl)[i] = ((const uint4*)Wdec)[i];
    __syncthreads();

    const int lane = tid & 63;
    int wid = blockIdx.x * 4 + (tid >> 6);
    const int nwaves = gridDim.x * 4;

    for (int row = wid; row < rows; row += nwaves){
        float lat[16];
        #pragma unroll
        for (int i = 0; i < 16; i++)
            lat[i] = b2f(latent[(size_t)row * H_ + i*64 + lane]);
        float acc[A_];
        #pragma unroll
        for (int a = 0; a < A_; a++) acc[a] = 0.f;
        #pragma unroll
        for (int i = 0; i < 16; i++){
            #pragma unroll
            for (int a = 0; a < A_; a++)
                acc[a] += lat[i] * b2f(wl[a * H_ + i*64 + lane]);
        }
        float m = mask[row];
        #pragma unroll
        for (int a = 0; a < A_; a++){
            float v = acc[a];
            #pragma unroll
            for (int s = 32; s > 0; s >>= 1) v += __shfl_down(v, s, 64);
            if (lane == 0) values[(size_t)row * A_ + a] = (v + bdec[a]) * m;
        }
    }
}

// ---------------- launcher ----------------

extern "C" void kernel_launch(void* const* d_in, const int* in_sizes, int n_in,
                              void* d_out, int out_size, void* d_ws, size_t ws_size,
                              hipStream_t stream)
{
    const float* obs  = (const float*)d_in[0];
    const float* mask = (const float*)d_in[1];
    const float* Wenc = (const float*)d_in[2];
    const float* benc = (const float*)d_in[3];
    const float* Wih  = (const float*)d_in[4];
    const float* bih  = (const float*)d_in[5];
    const float* Whh  = (const float*)d_in[6];
    const float* bhh  = (const float*)d_in[7];
    const float* Wdec = (const float*)d_in[8];
    const float* bdec = (const float*)d_in[9];
    float* out = (float*)d_out;

    char* p = (char*)d_ws;
    size_t o = 0;
    auto alloc = [&](size_t bytes){ void* r = p + o; o += (bytes + 255) & ~(size_t)255; return r; };
    u16*      wenc_b  = (u16*)     alloc((size_t)H_ * OBS_ * 2);
    u16*      wih_b   = (u16*)     alloc((size_t)G4_ * H_ * 2);
    u16*      whh_b   = (u16*)     alloc((size_t)G4_ * H_ * 2);
    u16*      wdec_b  = (u16*)     alloc((size_t)A_ * H_ * 2);
    float*    bias2   = (float*)   alloc((size_t)G4_ * 4);
    u16*      obs_b   = (u16*)     alloc((size_t)MM_ * OBS_ * 2);  // 33.6 MB
    float*    h_f32   = (float*)   alloc((size_t)B_ * H_ * 4);
    float*    c_f32   = (float*)   alloc((size_t)B_ * H_ * 4);
    unsigned* flags   = (unsigned*)alloc(1024 * 4);  // [4][64][4] u32

    const size_t hall_b    = (size_t)(T_ + 1) * B_ * H_ * 2;   // 67.2 MB
    const size_t enc_all_b = (size_t)MM_ * H_ * 2;             // 67.1 MB
    const size_t xg_all_b  = (size_t)MM_ * G4_ * 2;            // 268.4 MB
    const bool big = ws_size >= o + hall_b + enc_all_b + xg_all_b + 65536;
    (void)in_sizes; (void)n_in; (void)out_size;

    if (big){
        u16* h_all   = (u16*)alloc(hall_b);
        u16* enc_all = (u16*)alloc(enc_all_b);
        u16* xg_all  = (u16*)alloc(xg_all_b);

        prep_all<<<2048, 256, 0, stream>>>(Wenc, Wih, Whh, Wdec, bih, bhh, obs,
                                           wenc_b, wih_b, whh_b, wdec_b,
                                           bias2, obs_b, h_all, c_f32, flags);

        // enc for ALL T (34 GFLOP)
        dim3 ge(H_ / 128, MM_ / 128);
        gemm_bt<true><<<ge, 256, 0, stream>>>(
            obs_b, wenc_b, benc, enc_all, MM_, H_, OBS_);

        // xg for ALL T (274 GFLOP, full-GPU: 8192 tiles)
        dim3 gx(G4_ / 128, MM_ / 128);
        gemm_bt<false><<<gx, 256, 0, stream>>>(
            enc_all, wih_b, bias2, xg_all, MM_, G4_, H_);

        // ONE 512-step scan
        lstm_scan<<<256, 256, 0, stream>>>(
            xg_all, whh_b, h_all, c_f32, h_f32, mask, flags, 0, T_, nullptr);

        // ONE decode over all T
        decode_kernel<<<2048, 256, 0, stream>>>(
            h_all + (size_t)B_ * H_, wdec_b, bdec, mask, out, MM_);
    } else {
        // fallback: R4 chunked schedule (same kernels)
        u16* h_hist = (u16*)alloc((size_t)(CH_ + 1) * B_ * H_ * 2);  // 8.5 MB
        u16* enc_ch = (u16*)alloc((size_t)CM_ * H_ * 2);             // 8.4 MB
        u16* xg_ch  = (u16*)alloc((size_t)CM_ * G4_ * 2);            // 33.6 MB

        prep_all<<<2048, 256, 0, stream>>>(Wenc, Wih, Whh, Wdec, bih, bhh, obs,
                                           wenc_b, wih_b, whh_b, wdec_b,
                                           bias2, obs_b, h_hist, c_f32, flags);

        for (int c = 0; c < NCH_; c++){
            const int t0 = c * CH_;

            dim3 g1(H_ / 128, CM_ / 128);
            gemm_bt<true><<<g1, 256, 0, stream>>>(
                obs_b + (size_t)t0 * B_ * OBS_, wenc_b, benc, enc_ch, CM_, H_, OBS_);

            dim3 g2(G4_ / 128, CM_ / 128);
            gemm_bt<false><<<g2, 256, 0, stream>>>(
                enc_ch, wih_b, bias2, xg_ch, CM_, G4_, H_);

            lstm_scan<<<256, 256, 0, stream>>>(
                xg_ch, whh_b, h_hist, c_f32, h_f32,
                mask + (size_t)t0 * B_, flags, t0, CH_, h_hist);

            decode_kernel<<<256, 256, 0, stream>>>(
                h_hist + (size_t)B_ * H_, wdec_b, bdec, mask + (size_t)t0 * B_,
                out + (size_t)t0 * B_ * A_, CM_);
        }
    }

    copy_hc<<<256, 256, 0, stream>>>(h_f32, c_f32, out);
}

// Round 6
// 2555.390 us; speedup vs baseline: 1.0376x; 1.0376x over previous
//
#include <hip/hip_runtime.h>
#include <hip/hip_bf16.h>

#define T_ 512
#define B_ 64
#define OBS_ 512
#define H_ 1024
#define A_ 18
#define MM_ (T_*B_)   // 32768
#define G4_ (4*H_)    // 4096
#define CH_ 64        // fallback: time steps per chunk
#define NCH_ (T_/CH_) // 8 chunks
#define CM_ (CH_*B_)  // 4096 rows per chunk

typedef unsigned short u16;
typedef unsigned long long u64;
typedef __attribute__((ext_vector_type(8))) short s8v;
typedef __attribute__((ext_vector_type(4))) float f4v;

__device__ __forceinline__ float b2f(u16 u){
    unsigned x = ((unsigned)u) << 16;
    return __builtin_bit_cast(float, x);
}
__device__ __forceinline__ u16 f2b(float f){
    unsigned x = __builtin_bit_cast(unsigned, f);
    return (u16)((x + 0x7fffu + ((x >> 16) & 1u)) >> 16);  // RNE
}

// fast sigmoid/tanh: v_exp + v_rcp (error << bf16 quantum; correct at +-inf)
__device__ __forceinline__ float fsig(float x){
    return __builtin_amdgcn_rcpf(1.f + __expf(-x));
}
__device__ __forceinline__ float ftanh(float x){
    return 1.f - 2.f * __builtin_amdgcn_rcpf(__expf(2.f * x) + 1.f);
}

// ---------------- prologue: all casts + bias + zeroing in ONE dispatch ----------------

__global__ void prep_all(const float* __restrict__ Wenc, const float* __restrict__ Wih,
                         const float* __restrict__ Whh, const float* __restrict__ Wdec,
                         const float* __restrict__ bih, const float* __restrict__ bhh,
                         u16* __restrict__ wenc_b, u16* __restrict__ wih_b,
                         u16* __restrict__ whh_b, u16* __restrict__ wdec_b,
                         float* __restrict__ bias2, u16* __restrict__ h0buf,
                         float* __restrict__ c_f32, unsigned* __restrict__ flags)
{
    int i = blockIdx.x * blockDim.x + threadIdx.x;
    int stride = gridDim.x * blockDim.x;
    for (int k = i; k < G4_ * H_; k += stride){
        wih_b[k] = f2b(Wih[k]);
        whh_b[k] = f2b(Whh[k]);
    }
    for (int k = i; k < H_ * OBS_; k += stride) wenc_b[k] = f2b(Wenc[k]);
    for (int k = i; k < A_ * H_; k += stride) wdec_b[k] = f2b(Wdec[k]);
    for (int k = i; k < G4_; k += stride) bias2[k] = bih[k] + bhh[k];
    unsigned* h0 = (unsigned*)h0buf;
    for (int k = i; k < B_ * H_ / 2; k += stride) h0[k] = 0u;
    for (int k = i; k < B_ * H_; k += stride) c_f32[k] = 0.f;
    for (int k = i; k < 1024; k += stride) flags[k] = 0u;
}

__global__ void copy_hc(const float* __restrict__ h, const float* __restrict__ c,
                        float* __restrict__ out){
    int i = blockIdx.x * blockDim.x + threadIdx.x;  // 65536 threads
    out[(size_t)MM_*A_ + i] = h[i];
    out[(size_t)MM_*A_ + B_*H_ + i] = c[i];
}

// ---------------- enc GEMM (proven R4 structure): enc = relu(obs @ Wenc^T + benc) ----

#define LDSS 72  // 64 + 8 pad

__global__ __launch_bounds__(256) void gemm_enc(
    const float* __restrict__ A, const u16* __restrict__ W,
    const float* __restrict__ bias, u16* __restrict__ C,
    int M, int N, int K)
{
    __shared__ __align__(16) u16 As[128 * LDSS];
    __shared__ __align__(16) u16 Bs[128 * LDSS];

    const int tid  = threadIdx.x;
    const int lane = tid & 63;
    const int wid  = tid >> 6;
    const int wm   = wid & 1, wn = wid >> 1;
    const int m0   = blockIdx.y * 128, n0 = blockIdx.x * 128;
    const int quad = lane >> 4, l16 = lane & 15;

    f4v acc[4][4];
    #pragma unroll
    for (int i = 0; i < 4; i++)
        #pragma unroll
        for (int j = 0; j < 4; j++) acc[i][j] = (f4v){0.f,0.f,0.f,0.f};

    for (int k0 = 0; k0 < K; k0 += 64){
        __syncthreads();
        #pragma unroll
        for (int pss = 0; pss < 8; pss++){
            int idx = pss * 256 + tid;
            int row = idx >> 4, ch = idx & 15;
            float4 v = *(const float4*)(A + (size_t)(m0 + row) * K + k0 + ch * 4);
            u16* d = &As[row * LDSS + ch * 4];
            d[0] = f2b(v.x); d[1] = f2b(v.y); d[2] = f2b(v.z); d[3] = f2b(v.w);
        }
        #pragma unroll
        for (int pss = 0; pss < 4; pss++){
            int idx = pss * 256 + tid;
            int row = idx >> 3, ch = idx & 7;
            *(uint4*)&Bs[row * LDSS + ch * 8] =
                *(const uint4*)(W + (size_t)(n0 + row) * K + k0 + ch * 8);
        }
        __syncthreads();

        #pragma unroll
        for (int kk = 0; kk < 64; kk += 32){
            s8v af[4], bf[4];
            #pragma unroll
            for (int mt = 0; mt < 4; mt++)
                af[mt] = *(const s8v*)&As[(wm*64 + mt*16 + l16) * LDSS + kk + quad*8];
            #pragma unroll
            for (int nt = 0; nt < 4; nt++)
                bf[nt] = *(const s8v*)&Bs[(wn*64 + nt*16 + l16) * LDSS + kk + quad*8];
            #pragma unroll
            for (int mt = 0; mt < 4; mt++)
                #pragma unroll
                for (int nt = 0; nt < 4; nt++)
                    acc[mt][nt] = __builtin_amdgcn_mfma_f32_16x16x32_bf16(
                        af[mt], bf[nt], acc[mt][nt], 0, 0, 0);
        }
    }

    #pragma unroll
    for (int mt = 0; mt < 4; mt++){
        #pragma unroll
        for (int nt = 0; nt < 4; nt++){
            #pragma unroll
            for (int r = 0; r < 4; r++){
                int m = m0 + wm*64 + mt*16 + quad*4 + r;
                int n = n0 + wn*64 + nt*16 + l16;
                C[(size_t)m * N + n] = f2b(fmaxf(acc[mt][nt][r] + bias[n], 0.f));
            }
        }
    }
}

// ---------------- persistent LSTM scan, SELF-FEEDING (enc folded in) ----------------
// 256 blocks = 4 batch-groups (16 rows) x 64 N-slices (16 units). R4 per-wave
// flag protocol verbatim (R5's pipelined poll reverted: it cost ~11us/chunk).
// NEW: gates = enc@Wih^T + bias2 + h@Whh^T computed entirely in-kernel. Each
// wave holds BOTH Whh and Wih fragments in registers (same [m89] layout; the
// two matmuls have identical shape). Per step, the enc partial (no h
// dependency) runs BEFORE the flag poll on A-frags prefetched one step ahead
// from LLC-resident enc; the h partial accumulates into the same acc after
// the poll. The xg pipeline (268 MB buffer + 8 GEMM dispatches + HBM stream)
// disappears, and with nothing left between chunks, ONE dispatch runs all 512
// steps (no per-chunk Whh reload / launch ramps). bias2 lives in 4 regs.

__global__ __launch_bounds__(256, 1) void lstm_scan(
    const u16* __restrict__ enc,     // [nsteps*64][1024] bf16 (chunk-local)
    const u16* __restrict__ Wih,     // [4096][1024]
    const u16* __restrict__ Whh,     // [4096][1024]
    const float* __restrict__ bias2, // [4096] = bih + bhh
    u16* __restrict__ h_hist,        // [nsteps+1][64][1024]; [0] = incoming h
    float* __restrict__ c_glob,      // [64][1024] fp32
    float* __restrict__ h_f32,       // final-h staging (t == T-1 only)
    const float* __restrict__ mask,  // [nsteps][64]
    unsigned* __restrict__ flags,    // [4][64][4] per-wave monotonic step flags
    int t0, int nsteps, u16* __restrict__ seed)
{
    __shared__ float red[4][4][16][17];  // [wave][gate][batch][unit(+pad)] ~17.4 KB

    const int tid  = threadIdx.x;
    const int lane = tid & 63;
    const int w    = tid >> 6;
    const int quad = lane >> 4, l16 = lane & 15;
    const int bid  = blockIdx.x;
    const int g = bid & 3, s = bid >> 2;
    const int rb0 = g * 16, j0 = s * 16;

    // B-fragments for BOTH weight matrices: B[n=lane&15][k=quad*8+j] [m89]
    const int koff = w * 256;
    s8v bf[4][8], wf[4][8];
    #pragma unroll
    for (int gate = 0; gate < 4; gate++)
        #pragma unroll
        for (int ks = 0; ks < 8; ks++){
            size_t off = (size_t)(gate * H_ + j0 + l16) * H_ + koff + ks * 32 + quad * 8;
            bf[gate][ks] = *(const s8v*)(Whh + off);
            wf[gate][ks] = *(const s8v*)(Wih + off);
        }

    const int cb = tid >> 4, cu = tid & 15;
    const size_t cidx = (size_t)(rb0 + cb) * H_ + j0 + cu;
    float c_reg = c_glob[cidx];

    // per-thread bias (replaces the old xg-carried bias)
    float br[4];
    #pragma unroll
    for (int gate = 0; gate < 4; gate++) br[gate] = bias2[gate * H_ + j0 + cu];

    const size_t hoff = (size_t)(rb0 + l16) * H_ + koff + quad * 8;  // u16 elems
    const size_t eoff = (size_t)(rb0 + l16) * H_ + koff + quad * 8;  // same shape

    // producer: flags[g][s][w]; consumer wave w: flags[g][16w + lane>>2][lane&3]
    unsigned* myflag = flags + (g << 8) + (s << 2) + w;
    const unsigned* pollp = flags + (g << 8) + (w << 6) + lane;

    // prefetch enc A-frags + mask for st = 0
    s8v ef[8];
    {
        const u16* es = enc + eoff;  // time 0
        #pragma unroll
        for (int ks = 0; ks < 8; ks++) ef[ks] = *(const s8v*)(es + ks * 32);
    }
    float nm = mask[rb0 + cb];

    for (int st = 0; st < nsteps; st++){
        const float m = nm;

        // ---- enc partial: no h dependency -- runs before/under the wait
        f4v acc[4];
        #pragma unroll
        for (int gate = 0; gate < 4; gate++) acc[gate] = (f4v){0.f,0.f,0.f,0.f};
        #pragma unroll
        for (int ks = 0; ks < 8; ks++)
            #pragma unroll
            for (int gate = 0; gate < 4; gate++)
                acc[gate] = __builtin_amdgcn_mfma_f32_16x16x32_bf16(ef[ks], wf[gate][ks], acc[gate], 0, 0, 0);

        // ---- per-wave flag poll (R4 form): 16 producer blocks x 4 waves
        const unsigned tgt = (unsigned)(t0 + st);
        int tries = 0;
        for (;;){
            unsigned f = __hip_atomic_load(pollp, __ATOMIC_RELAXED, __HIP_MEMORY_SCOPE_AGENT);
            if (__all((int)(f >= tgt))) break;
            if (++tries > (1 << 20)) break;  // backstop: fail visibly, never hang
            if (tries >= 8) __builtin_amdgcn_s_sleep(1);
        }

        // ---- h partial (fresh: first touch after gate) into the same acc
        const u16* hs = h_hist + (size_t)st * B_ * H_ + hoff;
        #pragma unroll
        for (int ks = 0; ks < 8; ks++){
            s8v af = *(const s8v*)(hs + ks * 32);
            #pragma unroll
            for (int gate = 0; gate < 4; gate++)
                acc[gate] = __builtin_amdgcn_mfma_f32_16x16x32_bf16(af, bf[gate][ks], acc[gate], 0, 0, 0);
        }
        #pragma unroll
        for (int gate = 0; gate < 4; gate++)
            #pragma unroll
            for (int r = 0; r < 4; r++)
                red[w][gate][quad * 4 + r][l16] = acc[gate][r];
        __syncthreads();  // SYNC1: red[] complete before cell reads

        // ---- cell phase (fast transcendental forms)
        float gi = br[0], gf = br[1], gg = br[2], go = br[3];
        #pragma unroll
        for (int ww = 0; ww < 4; ww++){
            gi += red[ww][0][cb][cu];
            gf += red[ww][1][cb][cu];
            gg += red[ww][2][cb][cu];
            go += red[ww][3][cb][cu];
        }

        float is = fsig(gi);
        float fs = fsig(gf);
        float os = fsig(go);
        float gt = ftanh(gg);

        float cn = fs * c_reg + is * gt;
        float hn = os * ftanh(cn);
        hn *= m; cn *= m;
        c_reg = cn;
        if (t0 + st == T_ - 1) h_f32[cidx] = hn;

        // ---- publish h(st+1): packed u32 sc1 store to LLC (this wave: rows 4w..4w+3)
        unsigned hb = (unsigned)f2b(hn);
        unsigned partner = (unsigned)__shfl_xor((int)hb, 1, 64);
        if ((cu & 1) == 0){
            unsigned packed = hb | (partner << 16);
            unsigned* dst = (unsigned*)(h_hist + (size_t)(st + 1) * B_ * H_ + cidx);
            __hip_atomic_store(dst, packed, __ATOMIC_RELAXED, __HIP_MEMORY_SCOPE_AGENT);
            if (seed && st == nsteps - 1){  // seed next chunk's h[0] (fallback only)
                unsigned* dst0 = (unsigned*)(seed + cidx);
                __hip_atomic_store(dst0, packed, __ATOMIC_RELAXED, __HIP_MEMORY_SCOPE_AGENT);
            }
        }
        asm volatile("s_waitcnt vmcnt(0)" ::: "memory");  // this wave's h stores acked

        // ---- release: THIS WAVE's flag (covers exactly this wave's stores)
        if (lane == 0)
            __hip_atomic_store(myflag, (unsigned)(t0 + st + 1),
                               __ATOMIC_RELAXED, __HIP_MEMORY_SCOPE_AGENT);

        // ---- prefetch next step's enc frags + mask (overlaps next poll)
        if (st + 1 < nsteps){
            const u16* es = enc + (size_t)(st + 1) * B_ * H_ + eoff;
            #pragma unroll
            for (int ks = 0; ks < 8; ks++) ef[ks] = *(const s8v*)(es + ks * 32);
            nm = mask[(size_t)(st + 1) * B_ + rb0 + cb];
        }

        __syncthreads();  // SYNC2 (off publish path): guards red[] reuse
    }

    c_glob[cidx] = c_reg;
}

// ---------------- decode ----------------

__global__ __launch_bounds__(256) void decode_kernel(
    const u16* __restrict__ latent, const u16* __restrict__ Wdec,
    const float* __restrict__ bdec, const float* __restrict__ mask,
    float* __restrict__ values, int rows)
{
    __shared__ __align__(16) u16 wl[A_ * H_];
    const int tid = threadIdx.x;
    for (int i = tid; i < A_ * H_ / 8; i += 256)
        ((uint4*)wl)[i] = ((const uint4*)Wdec)[i];
    __syncthreads();

    const int lane = tid & 63;
    int wid = blockIdx.x * 4 + (tid >> 6);
    const int nwaves = gridDim.x * 4;

    for (int row = wid; row < rows; row += nwaves){
        float lat[16];
        #pragma unroll
        for (int i = 0; i < 16; i++)
            lat[i] = b2f(latent[(size_t)row * H_ + i*64 + lane]);
        float acc[A_];
        #pragma unroll
        for (int a = 0; a < A_; a++) acc[a] = 0.f;
        #pragma unroll
        for (int i = 0; i < 16; i++){
            #pragma unroll
            for (int a = 0; a < A_; a++)
                acc[a] += lat[i] * b2f(wl[a * H_ + i*64 + lane]);
        }
        float m = mask[row];
        #pragma unroll
        for (int a = 0; a < A_; a++){
            float v = acc[a];
            #pragma unroll
            for (int s = 32; s > 0; s >>= 1) v += __shfl_down(v, s, 64);
            if (lane == 0) values[(size_t)row * A_ + a] = (v + bdec[a]) * m;
        }
    }
}

// ---------------- launcher ----------------

extern "C" void kernel_launch(void* const* d_in, const int* in_sizes, int n_in,
                              void* d_out, int out_size, void* d_ws, size_t ws_size,
                              hipStream_t stream)
{
    const float* obs  = (const float*)d_in[0];
    const float* mask = (const float*)d_in[1];
    const float* Wenc = (const float*)d_in[2];
    const float* benc = (const float*)d_in[3];
    const float* Wih  = (const float*)d_in[4];
    const float* bih  = (const float*)d_in[5];
    const float* Whh  = (const float*)d_in[6];
    const float* bhh  = (const float*)d_in[7];
    const float* Wdec = (const float*)d_in[8];
    const float* bdec = (const float*)d_in[9];
    float* out = (float*)d_out;

    char* p = (char*)d_ws;
    size_t o = 0;
    auto alloc = [&](size_t bytes){ void* r = p + o; o += (bytes + 255) & ~(size_t)255; return r; };
    u16*      wenc_b  = (u16*)     alloc((size_t)H_ * OBS_ * 2);
    u16*      wih_b   = (u16*)     alloc((size_t)G4_ * H_ * 2);
    u16*      whh_b   = (u16*)     alloc((size_t)G4_ * H_ * 2);
    u16*      wdec_b  = (u16*)     alloc((size_t)A_ * H_ * 2);
    float*    bias2   = (float*)   alloc((size_t)G4_ * 4);
    float*    h_f32   = (float*)   alloc((size_t)B_ * H_ * 4);
    float*    c_f32   = (float*)   alloc((size_t)B_ * H_ * 4);
    unsigned* flags   = (unsigned*)alloc(1024 * 4);  // [4][64][4] u32

    const size_t hall_b    = (size_t)(T_ + 1) * B_ * H_ * 2;   // 67.2 MB
    const size_t enc_all_b = (size_t)MM_ * H_ * 2;             // 67.1 MB
    const bool big = ws_size >= o + hall_b + enc_all_b + 65536; // ~153 MB total
    (void)in_sizes; (void)n_in; (void)out_size;

    if (big){
        u16* h_all   = (u16*)alloc(hall_b);
        u16* enc_all = (u16*)alloc(enc_all_b);

        prep_all<<<2048, 256, 0, stream>>>(Wenc, Wih, Whh, Wdec, bih, bhh,
                                           wenc_b, wih_b, whh_b, wdec_b,
                                           bias2, h_all, c_f32, flags);

        // enc for ALL T (34 GFLOP, one dispatch)
        dim3 ge(H_ / 128, MM_ / 128);
        gemm_enc<<<ge, 256, 0, stream>>>(obs, wenc_b, benc, enc_all, MM_, H_, OBS_);

        // ONE 512-step self-feeding scan (enc@Wih folded into idle time)
        lstm_scan<<<256, 256, 0, stream>>>(
            enc_all, wih_b, whh_b, bias2, h_all, c_f32, h_f32,
            mask, flags, 0, T_, nullptr);

        // ONE decode over all T
        decode_kernel<<<2048, 256, 0, stream>>>(
            h_all + (size_t)B_ * H_, wdec_b, bdec, mask, out, MM_);
    } else {
        // fallback: chunked schedule, same self-feeding scan (no xg anywhere)
        u16* h_hist = (u16*)alloc((size_t)(CH_ + 1) * B_ * H_ * 2);  // 8.5 MB
        u16* enc_ch = (u16*)alloc((size_t)CM_ * H_ * 2);             // 8.4 MB

        prep_all<<<2048, 256, 0, stream>>>(Wenc, Wih, Whh, Wdec, bih, bhh,
                                           wenc_b, wih_b, whh_b, wdec_b,
                                           bias2, h_hist, c_f32, flags);

        for (int c = 0; c < NCH_; c++){
            const int t0 = c * CH_;

            dim3 g1(H_ / 128, CM_ / 128);
            gemm_enc<<<g1, 256, 0, stream>>>(
                obs + (size_t)t0 * B_ * OBS_, wenc_b, benc, enc_ch, CM_, H_, OBS_);

            lstm_scan<<<256, 256, 0, stream>>>(
                enc_ch, wih_b, whh_b, bias2, h_hist, c_f32, h_f32,
                mask + (size_t)t0 * B_, flags, t0, CH_, h_hist);

            decode_kernel<<<256, 256, 0, stream>>>(
                h_hist + (size_t)B_ * H_, wdec_b, bdec, mask + (size_t)t0 * B_,
                out + (size_t)t0 * B_ * A_, CM_);
        }
    }

    copy_hc<<<256, 256, 0, stream>>>(h_f32, c_f32, out);
}

// Round 7
// 2549.279 us; speedup vs baseline: 1.0401x; 1.0024x over previous
//
#include <hip/hip_runtime.h>
#include <hip/hip_bf16.h>

#define T_ 512
#define B_ 64
#define OBS_ 512
#define H_ 1024
#define A_ 18
#define MM_ (T_*B_)   // 32768
#define G4_ (4*H_)    // 4096
#define CH_ 64        // fallback: time steps per chunk
#define NCH_ (T_/CH_) // 8 chunks
#define CM_ (CH_*B_)  // 4096 rows per chunk

typedef unsigned short u16;
typedef unsigned long long u64;
typedef __attribute__((ext_vector_type(8))) short s8v;
typedef __attribute__((ext_vector_type(4))) float f4v;

__device__ __forceinline__ float b2f(u16 u){
    unsigned x = ((unsigned)u) << 16;
    return __builtin_bit_cast(float, x);
}
__device__ __forceinline__ u16 f2b(float f){
    unsigned x = __builtin_bit_cast(unsigned, f);
    return (u16)((x + 0x7fffu + ((x >> 16) & 1u)) >> 16);  // RNE
}

// fast sigmoid/tanh: v_exp + v_rcp (error << bf16 quantum; correct at +-inf)
__device__ __forceinline__ float fsig(float x){
    return __builtin_amdgcn_rcpf(1.f + __expf(-x));
}
__device__ __forceinline__ float ftanh(float x){
    return 1.f - 2.f * __builtin_amdgcn_rcpf(__expf(2.f * x) + 1.f);
}

// ---------------- prologue: all casts + bias + zeroing in ONE dispatch ----------------

__global__ void prep_all(const float* __restrict__ Wenc, const float* __restrict__ Wih,
                         const float* __restrict__ Whh, const float* __restrict__ Wdec,
                         const float* __restrict__ bih, const float* __restrict__ bhh,
                         u16* __restrict__ wenc_b, u16* __restrict__ wih_b,
                         u16* __restrict__ whh_b, u16* __restrict__ wdec_b,
                         float* __restrict__ bias2, u16* __restrict__ h0buf,
                         float* __restrict__ c_f32, unsigned* __restrict__ flags)
{
    int i = blockIdx.x * blockDim.x + threadIdx.x;
    int stride = gridDim.x * blockDim.x;
    for (int k = i; k < G4_ * H_; k += stride){
        wih_b[k] = f2b(Wih[k]);
        whh_b[k] = f2b(Whh[k]);
    }
    for (int k = i; k < H_ * OBS_; k += stride) wenc_b[k] = f2b(Wenc[k]);
    for (int k = i; k < A_ * H_; k += stride) wdec_b[k] = f2b(Wdec[k]);
    for (int k = i; k < G4_; k += stride) bias2[k] = bih[k] + bhh[k];
    unsigned* h0 = (unsigned*)h0buf;
    for (int k = i; k < B_ * H_ / 2; k += stride) h0[k] = 0u;
    for (int k = i; k < B_ * H_; k += stride) c_f32[k] = 0.f;
    for (int k = i; k < 1024; k += stride) flags[k] = 0u;
}

__global__ void copy_hc(const float* __restrict__ h, const float* __restrict__ c,
                        float* __restrict__ out){
    int i = blockIdx.x * blockDim.x + threadIdx.x;  // 65536 threads
    out[(size_t)MM_*A_ + i] = h[i];
    out[(size_t)MM_*A_ + B_*H_ + i] = c[i];
}

// ---------------- enc GEMM (proven R4 structure): enc = relu(obs @ Wenc^T + benc) ----

#define LDSS 72  // 64 + 8 pad

__global__ __launch_bounds__(256) void gemm_enc(
    const float* __restrict__ A, const u16* __restrict__ W,
    const float* __restrict__ bias, u16* __restrict__ C,
    int M, int N, int K)
{
    __shared__ __align__(16) u16 As[128 * LDSS];
    __shared__ __align__(16) u16 Bs[128 * LDSS];

    const int tid  = threadIdx.x;
    const int lane = tid & 63;
    const int wid  = tid >> 6;
    const int wm   = wid & 1, wn = wid >> 1;
    const int m0   = blockIdx.y * 128, n0 = blockIdx.x * 128;
    const int quad = lane >> 4, l16 = lane & 15;

    f4v acc[4][4];
    #pragma unroll
    for (int i = 0; i < 4; i++)
        #pragma unroll
        for (int j = 0; j < 4; j++) acc[i][j] = (f4v){0.f,0.f,0.f,0.f};

    for (int k0 = 0; k0 < K; k0 += 64){
        __syncthreads();
        #pragma unroll
        for (int pss = 0; pss < 8; pss++){
            int idx = pss * 256 + tid;
            int row = idx >> 4, ch = idx & 15;
            float4 v = *(const float4*)(A + (size_t)(m0 + row) * K + k0 + ch * 4);
            u16* d = &As[row * LDSS + ch * 4];
            d[0] = f2b(v.x); d[1] = f2b(v.y); d[2] = f2b(v.z); d[3] = f2b(v.w);
        }
        #pragma unroll
        for (int pss = 0; pss < 4; pss++){
            int idx = pss * 256 + tid;
            int row = idx >> 3, ch = idx & 7;
            *(uint4*)&Bs[row * LDSS + ch * 8] =
                *(const uint4*)(W + (size_t)(n0 + row) * K + k0 + ch * 8);
        }
        __syncthreads();

        #pragma unroll
        for (int kk = 0; kk < 64; kk += 32){
            s8v af[4], bf[4];
            #pragma unroll
            for (int mt = 0; mt < 4; mt++)
                af[mt] = *(const s8v*)&As[(wm*64 + mt*16 + l16) * LDSS + kk + quad*8];
            #pragma unroll
            for (int nt = 0; nt < 4; nt++)
                bf[nt] = *(const s8v*)&Bs[(wn*64 + nt*16 + l16) * LDSS + kk + quad*8];
            #pragma unroll
            for (int mt = 0; mt < 4; mt++)
                #pragma unroll
                for (int nt = 0; nt < 4; nt++)
                    acc[mt][nt] = __builtin_amdgcn_mfma_f32_16x16x32_bf16(
                        af[mt], bf[nt], acc[mt][nt], 0, 0, 0);
        }
    }

    #pragma unroll
    for (int mt = 0; mt < 4; mt++){
        #pragma unroll
        for (int nt = 0; nt < 4; nt++){
            #pragma unroll
            for (int r = 0; r < 4; r++){
                int m = m0 + wm*64 + mt*16 + quad*4 + r;
                int n = n0 + wn*64 + nt*16 + l16;
                C[(size_t)m * N + n] = f2b(fmaxf(acc[mt][nt][r] + bias[n], 0.f));
            }
        }
    }
}

// ---------------- persistent LSTM scan, SELF-FEEDING, 1-step enc pipeline -------
// R6 structure with two fixes:
//  (1) enc partial is software-pipelined ONE FULL STEP: eacc(st+1) is computed
//      from ef (loaded >=1 step = ~4us earlier -- definitely arrived) in the
//      rendezvous shadow AFTER publish(st); ef is then immediately re-issued
//      for enc(st+2). Loop top is acc=eacc -> poll: no load wait and no MFMA
//      on the pre-poll serial path (R6 paid LLC latency there every step).
//      Single ef buffer suffices: consume-then-reissue. The mid-loop vmcnt(0)
//      only sees ef loads that are >=1 step old (free).
//  (2) bf/wf weight fragments pinned via asm "+v": VGPR counts (92/172 < the
//      256 regs the fragments need) say the compiler has been re-loading
//      loop-invariant weight frags from LLC inside the step loop. The pin
//      makes the loaded values asm-produced: they cannot be rematerialized.

__global__ __launch_bounds__(256, 1) void lstm_scan(
    const u16* __restrict__ enc,     // [nsteps*64][1024] bf16 (chunk-local)
    const u16* __restrict__ Wih,     // [4096][1024]
    const u16* __restrict__ Whh,     // [4096][1024]
    const float* __restrict__ bias2, // [4096] = bih + bhh
    u16* __restrict__ h_hist,        // [nsteps+1][64][1024]; [0] = incoming h
    float* __restrict__ c_glob,      // [64][1024] fp32
    float* __restrict__ h_f32,       // final-h staging (t == T-1 only)
    const float* __restrict__ mask,  // [nsteps][64]
    unsigned* __restrict__ flags,    // [4][64][4] per-wave monotonic step flags
    int t0, int nsteps, u16* __restrict__ seed)
{
    __shared__ float red[4][4][16][17];  // [wave][gate][batch][unit(+pad)] ~17.4 KB

    const int tid  = threadIdx.x;
    const int lane = tid & 63;
    const int w    = tid >> 6;
    const int quad = lane >> 4, l16 = lane & 15;
    const int bid  = blockIdx.x;
    const int g = bid & 3, s = bid >> 2;
    const int rb0 = g * 16, j0 = s * 16;

    // B-fragments for BOTH weight matrices: B[n=lane&15][k=quad*8+j] [m89]
    const int koff = w * 256;
    s8v bf[4][8], wf[4][8];
    #pragma unroll
    for (int gate = 0; gate < 4; gate++)
        #pragma unroll
        for (int ks = 0; ks < 8; ks++){
            size_t off = (size_t)(gate * H_ + j0 + l16) * H_ + koff + ks * 32 + quad * 8;
            bf[gate][ks] = *(const s8v*)(Whh + off);
            wf[gate][ks] = *(const s8v*)(Wih + off);
        }
    // pin: values become asm-produced -> compiler must keep them in registers
    #pragma unroll
    for (int gate = 0; gate < 4; gate++)
        #pragma unroll
        for (int ks = 0; ks < 8; ks++){
            asm volatile("" : "+v"(bf[gate][ks]));
            asm volatile("" : "+v"(wf[gate][ks]));
        }

    const int cb = tid >> 4, cu = tid & 15;
    const size_t cidx = (size_t)(rb0 + cb) * H_ + j0 + cu;
    float c_reg = c_glob[cidx];

    // per-thread bias (replaces the old xg-carried bias)
    float br[4];
    #pragma unroll
    for (int gate = 0; gate < 4; gate++) br[gate] = bias2[gate * H_ + j0 + cu];

    const size_t hoff = (size_t)(rb0 + l16) * H_ + koff + quad * 8;  // u16 elems
    const size_t eoff = hoff;                                        // same shape

    // producer: flags[g][s][w]; consumer wave w: flags[g][16w + lane>>2][lane&3]
    unsigned* myflag = flags + (g << 8) + (s << 2) + w;
    const unsigned* pollp = flags + (g << 8) + (w << 6) + lane;

    // ---- prologue: enc partial for st=0; issue ef <- enc(1)
    s8v ef[8];
    f4v eacc[4];
    {
        const u16* es = enc + eoff;  // time 0
        #pragma unroll
        for (int ks = 0; ks < 8; ks++) ef[ks] = *(const s8v*)(es + ks * 32);
        #pragma unroll
        for (int gate = 0; gate < 4; gate++) eacc[gate] = (f4v){0.f,0.f,0.f,0.f};
        #pragma unroll
        for (int ks = 0; ks < 8; ks++)
            #pragma unroll
            for (int gate = 0; gate < 4; gate++)
                eacc[gate] = __builtin_amdgcn_mfma_f32_16x16x32_bf16(
                    ef[ks], wf[gate][ks], eacc[gate], 0, 0, 0);
        if (nsteps > 1){
            const u16* en = enc + (size_t)B_ * H_ + eoff;  // time 1
            #pragma unroll
            for (int ks = 0; ks < 8; ks++) ef[ks] = *(const s8v*)(en + ks * 32);
        }
    }
    float nm = mask[rb0 + cb];

    for (int st = 0; st < nsteps; st++){
        const float m = nm;

        // ---- gates = enc partial (pipelined) ...
        f4v acc[4];
        #pragma unroll
        for (int gate = 0; gate < 4; gate++) acc[gate] = eacc[gate];

        // ---- per-wave flag poll (R4 form): 16 producer blocks x 4 waves
        const unsigned tgt = (unsigned)(t0 + st);
        int tries = 0;
        for (;;){
            unsigned f = __hip_atomic_load(pollp, __ATOMIC_RELAXED, __HIP_MEMORY_SCOPE_AGENT);
            if (__all((int)(f >= tgt))) break;
            if (++tries > (1 << 20)) break;  // backstop: fail visibly, never hang
            if (tries >= 8) __builtin_amdgcn_s_sleep(1);
        }

        // ---- ... + h partial (fresh: first touch after gate)
        const u16* hs = h_hist + (size_t)st * B_ * H_ + hoff;
        #pragma unroll
        for (int ks = 0; ks < 8; ks++){
            s8v af = *(const s8v*)(hs + ks * 32);
            #pragma unroll
            for (int gate = 0; gate < 4; gate++)
                acc[gate] = __builtin_amdgcn_mfma_f32_16x16x32_bf16(af, bf[gate][ks], acc[gate], 0, 0, 0);
        }
        #pragma unroll
        for (int gate = 0; gate < 4; gate++)
            #pragma unroll
            for (int r = 0; r < 4; r++)
                red[w][gate][quad * 4 + r][l16] = acc[gate][r];
        __syncthreads();  // SYNC1: red[] complete before cell reads

        // ---- cell phase (fast transcendental forms)
        float gi = br[0], gf = br[1], gg = br[2], go = br[3];
        #pragma unroll
        for (int ww = 0; ww < 4; ww++){
            gi += red[ww][0][cb][cu];
            gf += red[ww][1][cb][cu];
            gg += red[ww][2][cb][cu];
            go += red[ww][3][cb][cu];
        }

        float is = fsig(gi);
        float fs = fsig(gf);
        float os = fsig(go);
        float gt = ftanh(gg);

        float cn = fs * c_reg + is * gt;
        float hn = os * ftanh(cn);
        hn *= m; cn *= m;
        c_reg = cn;
        if (t0 + st == T_ - 1) h_f32[cidx] = hn;

        // ---- publish h(st+1): packed u32 sc1 store to LLC (this wave: rows 4w..4w+3)
        unsigned hb = (unsigned)f2b(hn);
        unsigned partner = (unsigned)__shfl_xor((int)hb, 1, 64);
        if ((cu & 1) == 0){
            unsigned packed = hb | (partner << 16);
            unsigned* dst = (unsigned*)(h_hist + (size_t)(st + 1) * B_ * H_ + cidx);
            __hip_atomic_store(dst, packed, __ATOMIC_RELAXED, __HIP_MEMORY_SCOPE_AGENT);
            if (seed && st == nsteps - 1){  // seed next chunk's h[0] (fallback only)
                unsigned* dst0 = (unsigned*)(seed + cidx);
                __hip_atomic_store(dst0, packed, __ATOMIC_RELAXED, __HIP_MEMORY_SCOPE_AGENT);
            }
        }
        asm volatile("s_waitcnt vmcnt(0)" ::: "memory");  // h stores acked (+stale ef loads: free)

        // ---- release: THIS WAVE's flag (covers exactly this wave's stores)
        if (lane == 0)
            __hip_atomic_store(myflag, (unsigned)(t0 + st + 1),
                               __ATOMIC_RELAXED, __HIP_MEMORY_SCOPE_AGENT);

        // ---- rendezvous shadow: enc partial for st+1 (operands ~1 step old),
        //      then reissue ef <- enc(st+2); mask prefetch
        if (st + 1 < nsteps){
            #pragma unroll
            for (int gate = 0; gate < 4; gate++) eacc[gate] = (f4v){0.f,0.f,0.f,0.f};
            #pragma unroll
            for (int ks = 0; ks < 8; ks++)
                #pragma unroll
                for (int gate = 0; gate < 4; gate++)
                    eacc[gate] = __builtin_amdgcn_mfma_f32_16x16x32_bf16(
                        ef[ks], wf[gate][ks], eacc[gate], 0, 0, 0);
            if (st + 2 < nsteps){
                const u16* en = enc + (size_t)(st + 2) * B_ * H_ + eoff;
                #pragma unroll
                for (int ks = 0; ks < 8; ks++) ef[ks] = *(const s8v*)(en + ks * 32);
            }
            nm = mask[(size_t)(st + 1) * B_ + rb0 + cb];
        }

        __syncthreads();  // SYNC2 (off publish path): guards red[] reuse
    }

    c_glob[cidx] = c_reg;
}

// ---------------- decode ----------------

__global__ __launch_bounds__(256) void decode_kernel(
    const u16* __restrict__ latent, const u16* __restrict__ Wdec,
    const float* __restrict__ bdec, const float* __restrict__ mask,
    float* __restrict__ values, int rows)
{
    __shared__ __align__(16) u16 wl[A_ * H_];
    const int tid = threadIdx.x;
    for (int i = tid; i < A_ * H_ / 8; i += 256)
        ((uint4*)wl)[i] = ((const uint4*)Wdec)[i];
    __syncthreads();

    const int lane = tid & 63;
    int wid = blockIdx.x * 4 + (tid >> 6);
    const int nwaves = gridDim.x * 4;

    for (int row = wid; row < rows; row += nwaves){
        float lat[16];
        #pragma unroll
        for (int i = 0; i < 16; i++)
            lat[i] = b2f(latent[(size_t)row * H_ + i*64 + lane]);
        float acc[A_];
        #pragma unroll
        for (int a = 0; a < A_; a++) acc[a] = 0.f;
        #pragma unroll
        for (int i = 0; i < 16; i++){
            #pragma unroll
            for (int a = 0; a < A_; a++)
                acc[a] += lat[i] * b2f(wl[a * H_ + i*64 + lane]);
        }
        float m = mask[row];
        #pragma unroll
        for (int a = 0; a < A_; a++){
            float v = acc[a];
            #pragma unroll
            for (int s = 32; s > 0; s >>= 1) v += __shfl_down(v, s, 64);
            if (lane == 0) values[(size_t)row * A_ + a] = (v + bdec[a]) * m;
        }
    }
}

// ---------------- launcher ----------------

extern "C" void kernel_launch(void* const* d_in, const int* in_sizes, int n_in,
                              void* d_out, int out_size, void* d_ws, size_t ws_size,
                              hipStream_t stream)
{
    const float* obs  = (const float*)d_in[0];
    const float* mask = (const float*)d_in[1];
    const float* Wenc = (const float*)d_in[2];
    const float* benc = (const float*)d_in[3];
    const float* Wih  = (const float*)d_in[4];
    const float* bih  = (const float*)d_in[5];
    const float* Whh  = (const float*)d_in[6];
    const float* bhh  = (const float*)d_in[7];
    const float* Wdec = (const float*)d_in[8];
    const float* bdec = (const float*)d_in[9];
    float* out = (float*)d_out;

    char* p = (char*)d_ws;
    size_t o = 0;
    auto alloc = [&](size_t bytes){ void* r = p + o; o += (bytes + 255) & ~(size_t)255; return r; };
    u16*      wenc_b  = (u16*)     alloc((size_t)H_ * OBS_ * 2);
    u16*      wih_b   = (u16*)     alloc((size_t)G4_ * H_ * 2);
    u16*      whh_b   = (u16*)     alloc((size_t)G4_ * H_ * 2);
    u16*      wdec_b  = (u16*)     alloc((size_t)A_ * H_ * 2);
    float*    bias2   = (float*)   alloc((size_t)G4_ * 4);
    float*    h_f32   = (float*)   alloc((size_t)B_ * H_ * 4);
    float*    c_f32   = (float*)   alloc((size_t)B_ * H_ * 4);
    unsigned* flags   = (unsigned*)alloc(1024 * 4);  // [4][64][4] u32

    const size_t hall_b    = (size_t)(T_ + 1) * B_ * H_ * 2;   // 67.2 MB
    const size_t enc_all_b = (size_t)MM_ * H_ * 2;             // 67.1 MB
    const bool big = ws_size >= o + hall_b + enc_all_b + 65536; // ~153 MB total
    (void)in_sizes; (void)n_in; (void)out_size;

    if (big){
        u16* h_all   = (u16*)alloc(hall_b);
        u16* enc_all = (u16*)alloc(enc_all_b);

        prep_all<<<2048, 256, 0, stream>>>(Wenc, Wih, Whh, Wdec, bih, bhh,
                                           wenc_b, wih_b, whh_b, wdec_b,
                                           bias2, h_all, c_f32, flags);

        // enc for ALL T (34 GFLOP, one dispatch)
        dim3 ge(H_ / 128, MM_ / 128);
        gemm_enc<<<ge, 256, 0, stream>>>(obs, wenc_b, benc, enc_all, MM_, H_, OBS_);

        // ONE 512-step self-feeding scan (enc@Wih pipelined into rendezvous shadow)
        lstm_scan<<<256, 256, 0, stream>>>(
            enc_all, wih_b, whh_b, bias2, h_all, c_f32, h_f32,
            mask, flags, 0, T_, nullptr);

        // ONE decode over all T
        decode_kernel<<<2048, 256, 0, stream>>>(
            h_all + (size_t)B_ * H_, wdec_b, bdec, mask, out, MM_);
    } else {
        // fallback: chunked schedule, same self-feeding scan (no xg anywhere)
        u16* h_hist = (u16*)alloc((size_t)(CH_ + 1) * B_ * H_ * 2);  // 8.5 MB
        u16* enc_ch = (u16*)alloc((size_t)CM_ * H_ * 2);             // 8.4 MB

        prep_all<<<2048, 256, 0, stream>>>(Wenc, Wih, Whh, Wdec, bih, bhh,
                                           wenc_b, wih_b, whh_b, wdec_b,
                                           bias2, h_hist, c_f32, flags);

        for (int c = 0; c < NCH_; c++){
            const int t0 = c * CH_;

            dim3 g1(H_ / 128, CM_ / 128);
            gemm_enc<<<g1, 256, 0, stream>>>(
                obs + (size_t)t0 * B_ * OBS_, wenc_b, benc, enc_ch, CM_, H_, OBS_);

            lstm_scan<<<256, 256, 0, stream>>>(
                enc_ch, wih_b, whh_b, bias2, h_hist, c_f32, h_f32,
                mask + (size_t)t0 * B_, flags, t0, CH_, h_hist);

            decode_kernel<<<256, 256, 0, stream>>>(
                h_hist + (size_t)B_ * H_, wdec_b, bdec, mask + (size_t)t0 * B_,
                out + (size_t)t0 * B_ * A_, CM_);
        }
    }

    copy_hc<<<256, 256, 0, stream>>>(h_f32, c_f32, out);
}